// Round 6
// baseline (926.774 us; speedup 1.0000x reference)
//
#include <hip/hip_runtime.h>

#define SEQ 1024
#define BN  512
#define NT  64

__global__ void zero_out_kernel(float* o) { o[0] = 0.0f; }

// DPP row-rotate of a float through update_dpp (ctrl must be a literal).
// bound_ctrl=true + full masks: pure permute, fold-friendly for v_fmac_dpp.
#define ROTF(v, ctrl) \
  __int_as_float(__builtin_amdgcn_update_dpp( \
      0, __float_as_int(v), (ctrl), 0xF, 0xF, true))

extern "C" __global__ __launch_bounds__(64, 1)
void crf_kernel(const float* __restrict__ emis,
                const int*   __restrict__ tags,
                const int*   __restrict__ mask,
                const float* __restrict__ startT,
                const float* __restrict__ endT,
                const float* __restrict__ trans,
                float* __restrict__ out)
{
    const int b    = blockIdx.x;
    const int lane = threadIdx.x;

    // LDS only for numerator lookups; the u-recurrence is 100% in-register.
    __shared__ __align__(16) float strans[NT * NT];
    __shared__ int spk[SEQ];

    // ---- one-time staging (single wave, in-order DS, no barriers) ----
    {
        const float4* t4 = (const float4*)trans;
        float4* s4 = (float4*)strans;
        #pragma unroll
        for (int k = 0; k < 16; ++k)
            s4[k * NT + lane] = t4[k * NT + lane];
    }
    #pragma unroll
    for (int c = 0; c < SEQ / NT; ++c) {
        int t = c * NT + lane;
        spk[t] = (tags[t * BN + b] & 0xFFFF) | (mask[t * BN + b] << 16);
    }
    __threadfence_block();

    // ---- probe ROW_ROR direction: del = +1 or 15 (== -1 mod 16) ----
    // ror:1 delivers lane ((lane+del)&15)|(lane&48)'s value to this lane.
    const int probe = __builtin_amdgcn_update_dpp(0, lane, 0x121, 0xF, 0xF, true);
    const int del   = (probe - lane) & 15;

    // ---- 64 band registers: B{k}_{r}[lane] = exp(T[src(k,r,lane)][lane]),
    // src = ((lane + del*r)&15) | ((lane&48) ^ 16k). Conflict-free ds_reads
    // (addr = src*64+lane -> bank = lane&31), one-time cost.
#define BDECL(k, r) \
    const float B##k##_##r = __expf( \
        strans[((((lane) + (del) * (r)) & 15) | (((lane) & 48) ^ (16 * (k)))) * NT + lane]);
#define BROW(r) BDECL(0, r) BDECL(1, r) BDECL(2, r) BDECL(3, r)
    BROW(0)  BROW(1)  BROW(2)  BROW(3)
    BROW(4)  BROW(5)  BROW(6)  BROW(7)
    BROW(8)  BROW(9)  BROW(10) BROW(11)
    BROW(12) BROW(13) BROW(14) BROW(15)
#undef BROW
#undef BDECL

    // ---- t = 0 init ----
    float em0    = emis[(0 * BN + b) * NT + lane];
    int   tg_p   = spk[0] & 0xFFFF;
    float alpha0 = startT[lane] + em0;
    float M = __int_as_float(__builtin_amdgcn_readfirstlane(__float_as_int(alpha0)));
    float u = __expf(alpha0 - M);
    float score = (lane == tg_p) ? alpha0 : 0.0f;
    int   lt    = tg_p;
    int   esum  = 0;

    int   pkC   = spk[1];
    float TrowC = strans[tg_p * NT + lane];

    // depth-4 emission prefetch (the only loop vmem)
    float emA = emis[(1 * BN + b) * NT + lane];
    float emB = emis[(2 * BN + b) * NT + lane];
    float emC = emis[(3 * BN + b) * NT + lane];
    float emD = emis[(4 * BN + b) * NT + lane];

    #pragma unroll 2
    for (int t = 1; t < SEQ; ++t) {
        const float em_t = emA;
        emA = emB; emB = emC; emC = emD;
        int tn = t + 4; if (tn > SEQ - 1) tn = SEQ - 1;
        emD = emis[(tn * BN + b) * NT + lane];

        const int   pk   = pkC;
        const int   tg_t = pk & 0xFFFF;
        const int   mk_t = pk >> 16;
        const float Trow = TrowC;

        int tp = t + 1; if (tp > SEQ - 1) tp = SEQ - 1;
        pkC   = spk[tp];
        TrowC = strans[tg_t * NT + lane];

        const float w = __expf(em_t);            // off the u-chain

        // group bases: x16/x32/x48 hold u[lane^16/32/48]; in flight while
        // the 16 u-based (k=0) FMAs below issue.
        const float x16 = __shfl_xor(u, 16, 64);
        const float x32 = __shfl_xor(u, 32, 64);
        const float x48 = __shfl_xor(u, 48, 64);

        // 64 terms: s_j = sum over (k,r) of rot_r(base_k) * B[k][r].
        // 8 accumulator chains, depth 8; DPP folds into v_fmac_f32.
        float a0, a1, a2, a3, a4, a5, a6, a7;
        a0 = u   * B0_0;
        a1 = x16 * B1_0;
        a2 = x32 * B2_0;
        a3 = x48 * B3_0;
        a4 = ROTF(u,   0x121) * B0_1;
        a5 = ROTF(x16, 0x121) * B1_1;
        a6 = ROTF(x32, 0x121) * B2_1;
        a7 = ROTF(x48, 0x121) * B3_1;
#define TRM(r, A0_, A1_, A2_, A3_)                                   \
        A0_ = fmaf(ROTF(u,   0x120 + (r)), B0_##r, A0_);             \
        A1_ = fmaf(ROTF(x16, 0x120 + (r)), B1_##r, A1_);             \
        A2_ = fmaf(ROTF(x32, 0x120 + (r)), B2_##r, A2_);             \
        A3_ = fmaf(ROTF(x48, 0x120 + (r)), B3_##r, A3_);
        TRM(2,  a0, a1, a2, a3)
        TRM(3,  a4, a5, a6, a7)
        TRM(4,  a0, a1, a2, a3)
        TRM(5,  a4, a5, a6, a7)
        TRM(6,  a0, a1, a2, a3)
        TRM(7,  a4, a5, a6, a7)
        TRM(8,  a0, a1, a2, a3)
        TRM(9,  a4, a5, a6, a7)
        TRM(10, a0, a1, a2, a3)
        TRM(11, a4, a5, a6, a7)
        TRM(12, a0, a1, a2, a3)
        TRM(13, a4, a5, a6, a7)
        TRM(14, a0, a1, a2, a3)
        TRM(15, a4, a5, a6, a7)
#undef TRM
        const float s  = ((a0 + a1) + (a2 + a3)) + ((a4 + a5) + (a6 + a7));
        const float sw = s * w;

        if (mk_t) {                               // wave-uniform
            u = sw;
            if (lane == tg_t) score += em_t + Trow;
            lt = tg_t;
        }

        if ((t & 3) == 0) {                       // deferred exact renorm
            int e = (__builtin_amdgcn_readfirstlane(__float_as_int(u)) >> 23) & 255;
            u = ldexpf(u, 127 - e);
            esum += e - 127;
        }
        tg_p = tg_t; (void)tg_p;
    }

    // ---- epilogue ----
    if (lane == lt) score += endT[lane];
    float v  = u * __expf(endT[lane]);
    float sp = score;
    #pragma unroll
    for (int off = 32; off > 0; off >>= 1) {
        v  += __shfl_xor(v,  off, 64);
        sp += __shfl_xor(sp, off, 64);
    }
    if (lane == 0) {
        float denom = M + (float)esum * 0.69314718055994531f + __logf(v);
        atomicAdd(out, sp - denom);
    }
}

extern "C" void kernel_launch(void* const* d_in, const int* in_sizes, int n_in,
                              void* d_out, int out_size, void* d_ws, size_t ws_size,
                              hipStream_t stream)
{
    const float* emis   = (const float*)d_in[0];
    const int*   tags   = (const int*)  d_in[1];
    const int*   mask   = (const int*)  d_in[2];
    const float* startT = (const float*)d_in[3];
    const float* endT   = (const float*)d_in[4];
    const float* trans  = (const float*)d_in[5];
    float* out = (float*)d_out;

    zero_out_kernel<<<1, 1, 0, stream>>>(out);
    crf_kernel<<<dim3(BN), dim3(NT), 0, stream>>>(emis, tags, mask,
                                                  startT, endT, trans, out);
}